// Round 13
// baseline (462.495 us; speedup 1.0000x reference)
//
#include <hip/hip_runtime.h>
#include <hip/hip_bf16.h>

// GAT, H=4 heads x D=16, O=64 out channels, F=256 in features.
// Round-13: launch-count reduction (8 -> 5) + stage overlap.
//  - proj_count_kernel: grid-partitioned fusion. Blocks [0,nproj) = proj
//    (W->bfrag conversion INLINED from global Wfc/Wres, wprep eliminated);
//    blocks [nproj,nproj+B) = bucket_count (data-independent -> overlap).
//  - scan_final folded into consumers: scatter/agg add bsums[idx>>10] when
//    reading histS (partial per-1024-chunk scans + chunk-offset array).
//  - agg_bucket: 128-dst buckets (r12's 64-dst doubled nRB, +19us scans),
//    512 thr, 16-edge unrolled gather (r12's win, kept).
// Measured ledger: r11 total 427.7 (agg 142, non-agg 286) | r12 439.1 (agg
// 134, nRB-doubling cost +19) | r0 455.3 | append 747 (r9) | LDS fp-atomic
// agg 1450 (r2-5). NO global atomics in the main path.
// Softmax max-subtraction omitted: scores O(1), exp safe in fp32,
// softmax shift-invariant -> identical result.

#define F_IN 256
#define O_OUT 64
#define NEG_SLOPE 0.2f
#define CHUNK 4096           // edges per block in bucket passes (782 blocks)
#define RMAX 2048            // max buckets supported by LDS hist
#define BSH 7                // bucket shift: 128 dst nodes per bucket
#define BSZ 128

using frag_ab = __attribute__((ext_vector_type(8))) short;   // 8 bf16
using frag_cd = __attribute__((ext_vector_type(4))) float;   // 4 fp32

__device__ __forceinline__ float lrelu(float x) {
    return x >= 0.0f ? x : NEG_SLOPE * x;
}

__device__ __forceinline__ unsigned short f2bf(float f) {
    unsigned int u = __float_as_uint(f);
    unsigned int r = (u + 0x7fffu + ((u >> 16) & 1u)) >> 16;   // RNE
    return (unsigned short)r;
}
__device__ __forceinline__ float bflo(unsigned int p) {
    return __uint_as_float(p << 16);
}
__device__ __forceinline__ float bfhi(unsigned int p) {
    return __uint_as_float(p & 0xffff0000u);
}

// ---------------------------------------------------------------------------
// Fused proj + bucket_count. Blocks [0,nproj): MFMA projection (W conversion
// inlined; wprep's index algebra: frag (j,ks) of wave w -> col=(2w+j)*16+
// (lane&15), kbase=ks*32+(lane>>4)*8). Blocks [nproj,nproj+B): LDS histogram
// of dst>>BSH -> histT[bin*B+b]. Independent stages -> run concurrently.
// ---------------------------------------------------------------------------
__global__ __launch_bounds__(256) void proj_count_kernel(
    const float* __restrict__ feat, const float* __restrict__ Wfc,
    const float* __restrict__ Wres, const float* __restrict__ attn_l,
    const float* __restrict__ attn_r, unsigned short* __restrict__ fsb,
    float* __restrict__ el, float* __restrict__ er, float* __restrict__ out,
    float* __restrict__ denom_zero, const int* __restrict__ dst,
    int* __restrict__ histT, int N, int E, int B, int R, int nproj)
{
    __shared__ __align__(16) unsigned short sA[64 * 280];   // 35840 B
    const int t = threadIdx.x;

    if ((int)blockIdx.x >= nproj) {
        // ---- bucket_count branch ----
        if (!histT) return;
        int b = blockIdx.x - nproj;
        int* h = (int*)sA;                       // R*4 <= 35840 for R<=8960
        for (int i = t; i < R; i += 256) h[i] = 0;
        __syncthreads();
        int base = b * CHUNK;
        for (int i = t; i < CHUNK; i += 256) {
            int e = base + i;
            if (e < E) atomicAdd(&h[dst[e] >> BSH], 1);
        }
        __syncthreads();
        for (int i = t; i < R; i += 256) histT[(size_t)i * B + b] = h[i];
        return;
    }

    // ---- proj branch ----
    const int lane = t & 63;
    const int w = t >> 6;
    const int n0 = blockIdx.x * 64;
    if (n0 >= N) return;

    frag_ab bfrag[2][8];
#pragma unroll
    for (int j = 0; j < 2; ++j) {
        int col = (2 * w + j) * 16 + (lane & 15);
        const float* Wrow = (col < 64) ? (Wfc + (size_t)col * 256)
                                       : (Wres + (size_t)(col - 64) * 256);
#pragma unroll
        for (int ks = 0; ks < 8; ++ks) {
            int kbase = ks * 32 + (lane >> 4) * 8;
            const float4* p = (const float4*)(Wrow + kbase);
            float4 va = p[0], vb = p[1];
            frag_ab f;
            f[0] = (short)f2bf(va.x); f[1] = (short)f2bf(va.y);
            f[2] = (short)f2bf(va.z); f[3] = (short)f2bf(va.w);
            f[4] = (short)f2bf(vb.x); f[5] = (short)f2bf(vb.y);
            f[6] = (short)f2bf(vb.z); f[7] = (short)f2bf(vb.w);
            bfrag[j][ks] = f;
        }
    }

    if (denom_zero && n0 * 4 + t < N * 4) denom_zero[n0 * 4 + t] = 0.0f;

    for (int i = 0; i < 8; ++i) {
        int f = i * 256 + t;
        int row = f >> 5, c8 = f & 31;
        int n = n0 + row;
        float4 v0 = make_float4(0.f, 0.f, 0.f, 0.f), v1 = v0;
        if (n < N) {
            const float4* p = (const float4*)(feat + (size_t)n * F_IN + c8 * 8);
            v0 = p[0]; v1 = p[1];
        }
        frag_ab pack;
        pack[0] = (short)f2bf(v0.x); pack[1] = (short)f2bf(v0.y);
        pack[2] = (short)f2bf(v0.z); pack[3] = (short)f2bf(v0.w);
        pack[4] = (short)f2bf(v1.x); pack[5] = (short)f2bf(v1.y);
        pack[6] = (short)f2bf(v1.z); pack[7] = (short)f2bf(v1.w);
        *(frag_ab*)(&sA[row * 280 + c8 * 8]) = pack;
    }
    __syncthreads();

    frag_cd acc[4][2];
#pragma unroll
    for (int rt = 0; rt < 4; ++rt)
#pragma unroll
        for (int j = 0; j < 2; ++j)
            acc[rt][j] = (frag_cd){0.f, 0.f, 0.f, 0.f};

#pragma unroll
    for (int ks = 0; ks < 8; ++ks) {
        frag_ab af[4];
#pragma unroll
        for (int rt = 0; rt < 4; ++rt) {
            int row = rt * 16 + (lane & 15);
            int c8 = ks * 4 + (lane >> 4);
            af[rt] = *(const frag_ab*)(&sA[row * 280 + c8 * 8]);
        }
#pragma unroll
        for (int rt = 0; rt < 4; ++rt)
#pragma unroll
            for (int j = 0; j < 2; ++j)
                acc[rt][j] = __builtin_amdgcn_mfma_f32_16x16x32_bf16(
                    af[rt], bfrag[j][ks], acc[rt][j], 0, 0, 0);
    }

    // epilogue: C/D layout col = lane&15, row = (lane>>4)*4 + reg  [m89]
    const int colq = lane & 15;
    const int quad = lane >> 4;
    if (w < 2) {
#pragma unroll
        for (int j = 0; j < 2; ++j) {
            int h = 2 * w + j;
            float al = attn_l[h * 16 + colq];
            float ar = attn_r[h * 16 + colq];
#pragma unroll
            for (int rt = 0; rt < 4; ++rt)
#pragma unroll
                for (int r = 0; r < 4; ++r) {
                    int node = n0 + rt * 16 + quad * 4 + r;
                    float v = acc[rt][j][r];
                    if (node < N) fsb[(size_t)node * O_OUT + h * 16 + colq] = f2bf(v);
                    float pl = v * al, pr = v * ar;
                    pl += __shfl_xor(pl, 1); pr += __shfl_xor(pr, 1);
                    pl += __shfl_xor(pl, 2); pr += __shfl_xor(pr, 2);
                    pl += __shfl_xor(pl, 4); pr += __shfl_xor(pr, 4);
                    pl += __shfl_xor(pl, 8); pr += __shfl_xor(pr, 8);
                    if (colq == 0 && node < N) {
                        el[(size_t)node * 4 + h] = pl;
                        er[(size_t)node * 4 + h] = pr;
                    }
                }
        }
    } else {
#pragma unroll
        for (int j = 0; j < 2; ++j) {
            int cb = 32 * (w - 2) + 16 * j;
#pragma unroll
            for (int rt = 0; rt < 4; ++rt)
#pragma unroll
                for (int r = 0; r < 4; ++r) {
                    int node = n0 + rt * 16 + quad * 4 + r;
                    if (node < N)
                        out[(size_t)node * O_OUT + cb + colq] = acc[rt][j][r];
                }
        }
    }
}

// ---------------------------------------------------------------------------
// Scan chain (partial): per-1024-chunk exclusive scans + chunk totals.
// scan_final is FOLDED into consumers (they add bsums[idx>>10]).
// ---------------------------------------------------------------------------
__global__ __launch_bounds__(256) void scan_block_kernel(
    const int* __restrict__ counts, int* __restrict__ outp,
    int* __restrict__ bsums, int n)
{
    int t = threadIdx.x;
    int base = blockIdx.x * 1024 + t * 4;
    int c0 = 0, c1 = 0, c2 = 0, c3 = 0;
    if (base + 3 < n) {
        int4 v = *(const int4*)(counts + base);
        c0 = v.x; c1 = v.y; c2 = v.z; c3 = v.w;
    } else {
        if (base     < n) c0 = counts[base];
        if (base + 1 < n) c1 = counts[base + 1];
        if (base + 2 < n) c2 = counts[base + 2];
        if (base + 3 < n) c3 = counts[base + 3];
    }
    int tsum = c0 + c1 + c2 + c3;
    int inc = tsum;
    int lane = t & 63, wid = t >> 6;
#pragma unroll
    for (int o = 1; o < 64; o <<= 1) {
        int v = __shfl_up(inc, o);
        if (lane >= o) inc += v;
    }
    __shared__ int wsum[4];
    if (lane == 63) wsum[wid] = inc;
    __syncthreads();
    int woff = 0;
#pragma unroll
    for (int w = 0; w < 4; ++w)
        if (w < wid) woff += wsum[w];
    int excl = woff + inc - tsum;
    int e0 = excl, e1 = excl + c0, e2 = e1 + c1, e3 = e2 + c2;
    if (base + 3 < n) {
        *(int4*)(outp + base) = make_int4(e0, e1, e2, e3);
    } else {
        if (base     < n) outp[base]     = e0;
        if (base + 1 < n) outp[base + 1] = e1;
        if (base + 2 < n) outp[base + 2] = e2;
        if (base + 3 < n) outp[base + 3] = e3;
    }
    if (t == 255) bsums[blockIdx.x] = wsum[0] + wsum[1] + wsum[2] + wsum[3];
}

__global__ void scan_bsums_kernel(int* __restrict__ bsums, int nb)
{
    int lane = threadIdx.x;   // 64 threads
    int carry = 0;
    for (int c = 0; c * 64 < nb; ++c) {
        int i = c * 64 + lane;
        int v = (i < nb) ? bsums[i] : 0;
        int inc = v;
#pragma unroll
        for (int o = 1; o < 64; o <<= 1) {
            int u = __shfl_up(inc, o);
            if (lane >= o) inc += u;
        }
        if (i < nb) bsums[i] = carry + inc - v;
        carry += __shfl(inc, 63);
    }
}

// ---------------------------------------------------------------------------
// Bucket pass C: LDS-atomic local rank; write packed (src<<BSH)|dstlow to
// sorted_pk at (histS[bin*B+b]+bsums[.>>10]) + rank. Runs are contiguous.
// ---------------------------------------------------------------------------
__global__ __launch_bounds__(256) void bucket_scatter_kernel(
    const int* __restrict__ src, const int* __restrict__ dst,
    const int* __restrict__ histS, const int* __restrict__ bsums,
    unsigned int* __restrict__ sorted_pk, int E, int B, int R)
{
    __shared__ int h[RMAX];
    __shared__ int basebin[RMAX];
    int b = blockIdx.x, t = threadIdx.x;
    for (int i = t; i < R; i += 256) {
        h[i] = 0;
        int idx = i * B + b;
        basebin[i] = histS[idx] + bsums[idx >> 10];   // folded scan_final
    }
    __syncthreads();
    int base = b * CHUNK;
    for (int i = t; i < CHUNK; i += 256) {
        int e = base + i;
        if (e < E) {
            int d = dst[e];
            int bin = d >> BSH;
            int rk = atomicAdd(&h[bin], 1);
            sorted_pk[basebin[bin] + rk] =
                ((unsigned int)src[e] << BSH) | (unsigned int)(d & (BSZ - 1));
        }
    }
}

// ---------------------------------------------------------------------------
// Merged build+agg: one block per bucket (128 dst, 512 threads / 8 waves).
// LDS hist/scan/bin of the bucket's contiguous sorted_pk run, then each
// wave runs the 64-lane gather loop on 16 dst, src from LDS.
// 16-edge unrolled main loop (named scalars; no runtime-indexed arrays).
// ---------------------------------------------------------------------------
__global__ __launch_bounds__(512) void agg_bucket_kernel(
    const int* __restrict__ histS, const int* __restrict__ bsums,
    const unsigned int* __restrict__ sorted_pk,
    const unsigned short* __restrict__ fsb, const float* __restrict__ el,
    const float* __restrict__ er, float* __restrict__ out,
    int N, int E, int B, int R)
{
    __shared__ int buf2[8192];                  // binned src values, 32 KiB
    __shared__ int hist[BSZ], scn[BSZ], cur[BSZ];
    const int r = blockIdx.x;
    const int t = threadIdx.x;
    int idx0 = r * B;
    int start = histS[idx0] + bsums[idx0 >> 10];          // folded scan_final
    int end;
    if (r + 1 < R) {
        int idx1 = (r + 1) * B;
        end = histS[idx1] + bsums[idx1 >> 10];
    } else {
        end = E;
    }
    if (start < 0) start = 0;
    if (end < start) end = start;
    if (end > E) end = E;                       // clamps: identity on correct data
    const int cnt = end - start;

    if (t < BSZ) { hist[t] = 0; cur[t] = 0; }
    __syncthreads();
    // pass 1: histogram over dstlow (coalesced global pk read, LDS int atomics)
    for (int i = t; i < cnt; i += 512)
        atomicAdd(&hist[sorted_pk[start + i] & (BSZ - 1)], 1);
    __syncthreads();
    if (t < BSZ) scn[t] = hist[t];
    __syncthreads();
    for (int o = 1; o < BSZ; o <<= 1) {
        int v = 0;
        if (t < BSZ && t >= o) v = scn[t - o];
        __syncthreads();
        if (t < BSZ) scn[t] += v;
        __syncthreads();
    }
    // pass 2: bin src values into LDS (scn inclusive; offset = scn - hist)
    const bool use_lds = (cnt <= 8192);
    if (use_lds) {
        for (int i = t; i < cnt; i += 512) {
            unsigned int pk = sorted_pk[start + i];
            int low = (int)(pk & (BSZ - 1));
            int rk = atomicAdd(&cur[low], 1);
            buf2[(scn[low] - hist[low]) + rk] = (int)(pk >> BSH);
        }
    }
    __syncthreads();

    // agg: wave w (0..7) handles dst r*128 + w*16 + j, j=0..15
    const int lane = t & 63;
    const int w = t >> 6;
    const int half = lane >> 5;
    const int c = lane & 31;           // channels 2c, 2c+1
    const int h = c >> 3;
    for (int j = 0; j < 16; ++j) {
        int dl = w * 16 + j;
        int d = r * BSZ + dl;
        if (d >= N) break;             // dl increasing -> all later invalid too
        const int k0 = scn[dl] - hist[dl];
        const int k1 = scn[dl];
        const float erh = er[(size_t)d * 4 + h];
        float a0 = 0.f, a1 = 0.f, den = 0.f;
        if (use_lds) {
            int kb = k0;
            // 16 edges per iteration: 8 el + 8 fsb loads in flight
            for (; kb + 16 <= k1; kb += 16) {
                int s0 = buf2[kb + 0 + half];
                int s1 = buf2[kb + 2 + half];
                int s2 = buf2[kb + 4 + half];
                int s3 = buf2[kb + 6 + half];
                int s4 = buf2[kb + 8 + half];
                int s5 = buf2[kb + 10 + half];
                int s6 = buf2[kb + 12 + half];
                int s7 = buf2[kb + 14 + half];
                float e0 = el[(size_t)s0 * 4 + h];
                float e1 = el[(size_t)s1 * 4 + h];
                float e2 = el[(size_t)s2 * 4 + h];
                float e3 = el[(size_t)s3 * 4 + h];
                float e4 = el[(size_t)s4 * 4 + h];
                float e5 = el[(size_t)s5 * 4 + h];
                float e6 = el[(size_t)s6 * 4 + h];
                float e7 = el[(size_t)s7 * 4 + h];
                unsigned int f0 = *(const unsigned int*)(fsb + (size_t)s0 * O_OUT + 2 * c);
                unsigned int f1 = *(const unsigned int*)(fsb + (size_t)s1 * O_OUT + 2 * c);
                unsigned int f2 = *(const unsigned int*)(fsb + (size_t)s2 * O_OUT + 2 * c);
                unsigned int f3 = *(const unsigned int*)(fsb + (size_t)s3 * O_OUT + 2 * c);
                unsigned int f4 = *(const unsigned int*)(fsb + (size_t)s4 * O_OUT + 2 * c);
                unsigned int f5 = *(const unsigned int*)(fsb + (size_t)s5 * O_OUT + 2 * c);
                unsigned int f6 = *(const unsigned int*)(fsb + (size_t)s6 * O_OUT + 2 * c);
                unsigned int f7 = *(const unsigned int*)(fsb + (size_t)s7 * O_OUT + 2 * c);
                float w0 = __expf(lrelu(e0 + erh));
                float w1 = __expf(lrelu(e1 + erh));
                float w2 = __expf(lrelu(e2 + erh));
                float w3 = __expf(lrelu(e3 + erh));
                float w4 = __expf(lrelu(e4 + erh));
                float w5 = __expf(lrelu(e5 + erh));
                float w6 = __expf(lrelu(e6 + erh));
                float w7 = __expf(lrelu(e7 + erh));
                a0 += w0 * bflo(f0); a1 += w0 * bfhi(f0); den += w0;
                a0 += w1 * bflo(f1); a1 += w1 * bfhi(f1); den += w1;
                a0 += w2 * bflo(f2); a1 += w2 * bfhi(f2); den += w2;
                a0 += w3 * bflo(f3); a1 += w3 * bfhi(f3); den += w3;
                a0 += w4 * bflo(f4); a1 += w4 * bfhi(f4); den += w4;
                a0 += w5 * bflo(f5); a1 += w5 * bfhi(f5); den += w5;
                a0 += w6 * bflo(f6); a1 += w6 * bfhi(f6); den += w6;
                a0 += w7 * bflo(f7); a1 += w7 * bfhi(f7); den += w7;
            }
            for (; kb + 8 <= k1; kb += 8) {
                int s0 = buf2[kb + half];
                int s1 = buf2[kb + 2 + half];
                int s2 = buf2[kb + 4 + half];
                int s3 = buf2[kb + 6 + half];
                float e0 = el[(size_t)s0 * 4 + h];
                float e1 = el[(size_t)s1 * 4 + h];
                float e2 = el[(size_t)s2 * 4 + h];
                float e3 = el[(size_t)s3 * 4 + h];
                unsigned int f0 = *(const unsigned int*)(fsb + (size_t)s0 * O_OUT + 2 * c);
                unsigned int f1 = *(const unsigned int*)(fsb + (size_t)s1 * O_OUT + 2 * c);
                unsigned int f2 = *(const unsigned int*)(fsb + (size_t)s2 * O_OUT + 2 * c);
                unsigned int f3 = *(const unsigned int*)(fsb + (size_t)s3 * O_OUT + 2 * c);
                float w0 = __expf(lrelu(e0 + erh));
                float w1 = __expf(lrelu(e1 + erh));
                float w2 = __expf(lrelu(e2 + erh));
                float w3 = __expf(lrelu(e3 + erh));
                a0 += w0 * bflo(f0); a1 += w0 * bfhi(f0); den += w0;
                a0 += w1 * bflo(f1); a1 += w1 * bfhi(f1); den += w1;
                a0 += w2 * bflo(f2); a1 += w2 * bfhi(f2); den += w2;
                a0 += w3 * bflo(f3); a1 += w3 * bfhi(f3); den += w3;
            }
            for (; kb < k1; kb += 2) {
                int ki = kb + half;
                if (ki < k1) {
                    int s = buf2[ki];
                    float wv = __expf(lrelu(el[(size_t)s * 4 + h] + erh));
                    unsigned int f = *(const unsigned int*)(fsb + (size_t)s * O_OUT + 2 * c);
                    a0 += wv * bflo(f); a1 += wv * bfhi(f); den += wv;
                }
            }
        } else {
            // fallback (cnt > 8192, not expected at bench sizes): filter scan
            for (int i2 = 0; i2 < cnt; i2 += 2) {
                int ki = i2 + half;
                if (ki < cnt) {
                    unsigned int pk = sorted_pk[start + ki];
                    if ((int)(pk & (BSZ - 1)) == dl) {
                        int s = (int)(pk >> BSH);
                        float wv = __expf(lrelu(el[(size_t)s * 4 + h] + erh));
                        unsigned int f = *(const unsigned int*)(fsb + (size_t)s * O_OUT + 2 * c);
                        a0 += wv * bflo(f); a1 += wv * bfhi(f); den += wv;
                    }
                }
            }
        }
        a0 += __shfl_xor(a0, 32);
        a1 += __shfl_xor(a1, 32);
        den += __shfl_xor(den, 32);
        if (half == 0) {
            float inv = 1.0f / fmaxf(den, 1e-20f);
            float2* po = (float2*)(out + (size_t)d * O_OUT + 2 * c);
            float2 o = *po;
            o.x += a0 * inv;
            o.y += a1 * inv;
            *po = o;
        }
    }
}

// ---------------------------------------------------------------------------
// Fallback path (small ws): no-max softmax, atomics, bf16 fs.
// ---------------------------------------------------------------------------
__global__ __launch_bounds__(256) void edge_sum_kernel(
    const int* __restrict__ src, const int* __restrict__ dst,
    const float* __restrict__ el, const float* __restrict__ er,
    float* __restrict__ denom, int E)
{
    int e = blockIdx.x * 256 + threadIdx.x;
    if (e >= E) return;
    int s = src[e], d = dst[e];
    float4 l4 = ((const float4*)el)[s];
    float4 r4 = ((const float4*)er)[d];
    unsafeAtomicAdd(&denom[(size_t)d * 4 + 0], __expf(lrelu(l4.x + r4.x)));
    unsafeAtomicAdd(&denom[(size_t)d * 4 + 1], __expf(lrelu(l4.y + r4.y)));
    unsafeAtomicAdd(&denom[(size_t)d * 4 + 2], __expf(lrelu(l4.z + r4.z)));
    unsafeAtomicAdd(&denom[(size_t)d * 4 + 3], __expf(lrelu(l4.w + r4.w)));
}

__global__ __launch_bounds__(256) void agg_atomic_kernel(
    const int* __restrict__ src, const int* __restrict__ dst,
    const unsigned short* __restrict__ fsb, const float* __restrict__ el,
    const float* __restrict__ er, const float* __restrict__ denom,
    float* __restrict__ out, int E)
{
    const int lane = threadIdx.x & 63;
    const int wid = threadIdx.x >> 6;
    int e = blockIdx.x * 4 + wid;
    if (e >= E) return;
    int s = src[e], d = dst[e];
    int h = lane >> 4;
    float v = __expf(lrelu(el[(size_t)s * 4 + h] + er[(size_t)d * 4 + h]));
    float alpha = v / fmaxf(denom[(size_t)d * 4 + h], 1e-20f);
    float fval = __uint_as_float(((unsigned int)fsb[(size_t)s * O_OUT + lane]) << 16);
    unsafeAtomicAdd(&out[(size_t)d * O_OUT + lane], alpha * fval);
}

extern "C" void kernel_launch(void* const* d_in, const int* in_sizes, int n_in,
                              void* d_out, int out_size, void* d_ws, size_t ws_size,
                              hipStream_t stream) {
    const float* feat   = (const float*)d_in[0];
    const float* Wfc    = (const float*)d_in[1];
    const float* attn_l = (const float*)d_in[2];
    const float* attn_r = (const float*)d_in[3];
    const float* Wres   = (const float*)d_in[4];
    const int*   src    = (const int*)d_in[5];
    const int*   dst    = (const int*)d_in[6];

    const int N = in_sizes[0] / F_IN;     // 100000
    const int E = in_sizes[5];            // 3200000
    float* out = (float*)d_out;

    const int R = (N + BSZ - 1) >> BSH;           // buckets of 128 nodes (782)
    const int B = (E + CHUNK - 1) / CHUNK;        // blocks in bucket passes
    const int nRB = R * B;
    const int nsb = (nRB + 1023) / 1024;

    // layout: el | er | histT[nRB] | histS[nRB+8] | bsums[1024] |
    //         sorted_pk[E] | fsb
    float* el     = (float*)d_ws;
    float* er     = el + (size_t)N * 4;
    int*   histT  = (int*)(er + (size_t)N * 4);
    int*   histS  = histT + nRB;
    int*   bsums  = histS + nRB + 8;
    unsigned int* sorted_pk = (unsigned int*)(bsums + 1024);
    unsigned short* fsb = (unsigned short*)(sorted_pk + E);
    size_t need_main = (size_t)((char*)(fsb + (size_t)N * O_OUT) - (char*)d_ws);

    int nproj = (N + 63) / 64;

    if (ws_size >= need_main && R <= RMAX && nsb <= 1024) {
        proj_count_kernel<<<nproj + B, 256, 0, stream>>>(
            feat, Wfc, Wres, attn_l, attn_r, fsb, el, er, out,
            nullptr, dst, histT, N, E, B, R, nproj);
        scan_block_kernel<<<nsb, 256, 0, stream>>>(histT, histS, bsums, nRB);
        scan_bsums_kernel<<<1, 64, 0, stream>>>(bsums, nsb);
        bucket_scatter_kernel<<<B, 256, 0, stream>>>(
            src, dst, histS, bsums, sorted_pk, E, B, R);
        agg_bucket_kernel<<<R, 512, 0, stream>>>(
            histS, bsums, sorted_pk, fsb, el, er, out, N, E, B, R);
    } else {
        // fallback: denom overlays histT region; fsb right after denom
        float* denom = (float*)histT;                 // [N*4]
        unsigned short* fsb2 = (unsigned short*)(denom + (size_t)N * 4);
        proj_count_kernel<<<nproj, 256, 0, stream>>>(
            feat, Wfc, Wres, attn_l, attn_r, fsb2, el, er, out,
            denom, nullptr, nullptr, N, E, 0, 0, nproj);
        edge_sum_kernel<<<(E + 255) / 256, 256, 0, stream>>>(src, dst, el, er, denom, E);
        agg_atomic_kernel<<<(E + 3) / 4, 256, 0, stream>>>(
            src, dst, fsb2, el, er, denom, out, E);
    }
}

// Round 14
// 429.834 us; speedup vs baseline: 1.0760x; 1.0760x over previous
//
#include <hip/hip_runtime.h>
#include <hip/hip_bf16.h>

// GAT, H=4 heads x D=16, O=64 out channels, F=256 in features.
// REVERT to round-11 (best measured: 427.7us). Round-12 (64-dst buckets,
// +19us scans) and round-13 (launch fusion + 512-thr unroll: agg 142->158,
// W re-conversion per block) both regressed; this is the measured optimum.
// Pipeline: wprep -> proj_mfma (bf16 MFMA: fc -> fsb bf16 + el/er logits,
// res -> out fp32) -> bucket_count (LDS hist over dst>>7) -> scan(3) ->
// bucket_scatter (LDS-rank, packed (src<<7|dstlow) runs per (bin,block)) ->
// agg_bucket (per-bucket LDS hist/scan/bin + 64-lane gather, src from LDS).
// CHUNK=4096: 782 blocks (~3/CU) -- r11 vs r10 isolated: -28us.
// Measured ledger: r11 total 427.7 (agg 142) | r12 439.1 | r13 462.5 |
// r0 455.3 (agg_csr 119.5) | global hist+scatter 597 (r6) | 782-head
// append 747 (r9) | LDS fp-atomic agg 1450 (r2-5).
// NO global atomics anywhere in the main path.
// Softmax max-subtraction omitted: scores O(1), exp safe in fp32,
// softmax shift-invariant -> identical result.

#define F_IN 256
#define O_OUT 64
#define NEG_SLOPE 0.2f
#define CHUNK 4096           // edges per block in bucket passes (782 blocks)
#define RMAX 2048            // max buckets supported by LDS hist

using frag_ab = __attribute__((ext_vector_type(8))) short;   // 8 bf16
using frag_cd = __attribute__((ext_vector_type(4))) float;   // 4 fp32

__device__ __forceinline__ float lrelu(float x) {
    return x >= 0.0f ? x : NEG_SLOPE * x;
}

__device__ __forceinline__ unsigned short f2bf(float f) {
    unsigned int u = __float_as_uint(f);
    unsigned int r = (u + 0x7fffu + ((u >> 16) & 1u)) >> 16;   // RNE
    return (unsigned short)r;
}
__device__ __forceinline__ float bflo(unsigned int p) {
    return __uint_as_float(p << 16);
}
__device__ __forceinline__ float bfhi(unsigned int p) {
    return __uint_as_float(p & 0xffff0000u);
}

// ---------------------------------------------------------------------------
// Weight prep: Wfc/Wres fp32 [64][256] -> Bf bf16 in MFMA B-frag lane order.
// ---------------------------------------------------------------------------
__global__ __launch_bounds__(256) void wprep_kernel(
    const float* __restrict__ Wfc, const float* __restrict__ Wres,
    unsigned short* __restrict__ Bf)
{
    int tid = blockIdx.x * 256 + threadIdx.x;   // 0..4095
    int ct = tid >> 9;
    int lane = tid & 63;
    int ks = (tid >> 6) & 7;
    int col = ct * 16 + (lane & 15);
    int kbase = ks * 32 + (lane >> 4) * 8;
    const float* srcW = (col < 64) ? (Wfc + (size_t)col * 256 + kbase)
                                   : (Wres + (size_t)(col - 64) * 256 + kbase);
    unsigned short* dstp = Bf + (size_t)tid * 8;
#pragma unroll
    for (int i = 0; i < 8; ++i) dstp[i] = f2bf(srcW[i]);
}

// ---------------------------------------------------------------------------
// MFMA projection: block = 256 threads (4 waves), 64 nodes.
// ---------------------------------------------------------------------------
__global__ __launch_bounds__(256) void proj_mfma_kernel(
    const float* __restrict__ feat, const unsigned short* __restrict__ Bf,
    const float* __restrict__ attn_l, const float* __restrict__ attn_r,
    unsigned short* __restrict__ fsb, float* __restrict__ el,
    float* __restrict__ er, float* __restrict__ out,
    float* __restrict__ denom_zero, int N)
{
    __shared__ __align__(16) unsigned short sA[64 * 280];   // 35840 B
    const int t = threadIdx.x;
    const int lane = t & 63;
    const int w = t >> 6;
    const int n0 = blockIdx.x * 64;
    if (n0 >= N) return;

    frag_ab bfrag[2][8];
    {
        const unsigned short* bp = Bf + (size_t)lane * 8;
#pragma unroll
        for (int j = 0; j < 2; ++j)
#pragma unroll
            for (int ks = 0; ks < 8; ++ks)
                bfrag[j][ks] = *(const frag_ab*)(bp + (size_t)((2 * w + j) * 8 + ks) * 512);
    }

    if (denom_zero && n0 * 4 + t < N * 4) denom_zero[n0 * 4 + t] = 0.0f;

    for (int i = 0; i < 8; ++i) {
        int f = i * 256 + t;
        int row = f >> 5, c8 = f & 31;
        int n = n0 + row;
        float4 v0 = make_float4(0.f, 0.f, 0.f, 0.f), v1 = v0;
        if (n < N) {
            const float4* p = (const float4*)(feat + (size_t)n * F_IN + c8 * 8);
            v0 = p[0]; v1 = p[1];
        }
        frag_ab pack;
        pack[0] = (short)f2bf(v0.x); pack[1] = (short)f2bf(v0.y);
        pack[2] = (short)f2bf(v0.z); pack[3] = (short)f2bf(v0.w);
        pack[4] = (short)f2bf(v1.x); pack[5] = (short)f2bf(v1.y);
        pack[6] = (short)f2bf(v1.z); pack[7] = (short)f2bf(v1.w);
        *(frag_ab*)(&sA[row * 280 + c8 * 8]) = pack;
    }
    __syncthreads();

    frag_cd acc[4][2];
#pragma unroll
    for (int rt = 0; rt < 4; ++rt)
#pragma unroll
        for (int j = 0; j < 2; ++j)
            acc[rt][j] = (frag_cd){0.f, 0.f, 0.f, 0.f};

#pragma unroll
    for (int ks = 0; ks < 8; ++ks) {
        frag_ab af[4];
#pragma unroll
        for (int rt = 0; rt < 4; ++rt) {
            int row = rt * 16 + (lane & 15);
            int c8 = ks * 4 + (lane >> 4);
            af[rt] = *(const frag_ab*)(&sA[row * 280 + c8 * 8]);
        }
#pragma unroll
        for (int rt = 0; rt < 4; ++rt)
#pragma unroll
            for (int j = 0; j < 2; ++j)
                acc[rt][j] = __builtin_amdgcn_mfma_f32_16x16x32_bf16(
                    af[rt], bfrag[j][ks], acc[rt][j], 0, 0, 0);
    }

    // epilogue: C/D layout col = lane&15, row = (lane>>4)*4 + reg  [m89]
    const int colq = lane & 15;
    const int quad = lane >> 4;
    if (w < 2) {
#pragma unroll
        for (int j = 0; j < 2; ++j) {
            int h = 2 * w + j;
            float al = attn_l[h * 16 + colq];
            float ar = attn_r[h * 16 + colq];
#pragma unroll
            for (int rt = 0; rt < 4; ++rt)
#pragma unroll
                for (int r = 0; r < 4; ++r) {
                    int node = n0 + rt * 16 + quad * 4 + r;
                    float v = acc[rt][j][r];
                    if (node < N) fsb[(size_t)node * O_OUT + h * 16 + colq] = f2bf(v);
                    float pl = v * al, pr = v * ar;
                    pl += __shfl_xor(pl, 1); pr += __shfl_xor(pr, 1);
                    pl += __shfl_xor(pl, 2); pr += __shfl_xor(pr, 2);
                    pl += __shfl_xor(pl, 4); pr += __shfl_xor(pr, 4);
                    pl += __shfl_xor(pl, 8); pr += __shfl_xor(pr, 8);
                    if (colq == 0 && node < N) {
                        el[(size_t)node * 4 + h] = pl;
                        er[(size_t)node * 4 + h] = pr;
                    }
                }
        }
    } else {
#pragma unroll
        for (int j = 0; j < 2; ++j) {
            int cb = 32 * (w - 2) + 16 * j;
#pragma unroll
            for (int rt = 0; rt < 4; ++rt)
#pragma unroll
                for (int r = 0; r < 4; ++r) {
                    int node = n0 + rt * 16 + quad * 4 + r;
                    if (node < N)
                        out[(size_t)node * O_OUT + cb + colq] = acc[rt][j][r];
                }
        }
    }
}

// ---------------------------------------------------------------------------
// Bucket pass A: per-block LDS histogram of dst>>7 -> histT[bin*B + b].
// ---------------------------------------------------------------------------
__global__ __launch_bounds__(256) void bucket_count_kernel(
    const int* __restrict__ dst, int* __restrict__ histT, int E, int B, int R)
{
    __shared__ int h[RMAX];
    int b = blockIdx.x, t = threadIdx.x;
    for (int i = t; i < R; i += 256) h[i] = 0;
    __syncthreads();
    int base = b * CHUNK;
    for (int i = t; i < CHUNK; i += 256) {
        int e = base + i;
        if (e < E) atomicAdd(&h[dst[e] >> 7], 1);
    }
    __syncthreads();
    for (int i = t; i < R; i += 256) histT[(size_t)i * B + b] = h[i];
}

// ---------------------------------------------------------------------------
// Scan chain (exclusive prefix sum over arbitrary n, 1024/block).
// ---------------------------------------------------------------------------
__global__ __launch_bounds__(256) void scan_block_kernel(
    const int* __restrict__ counts, int* __restrict__ outp,
    int* __restrict__ bsums, int n)
{
    int t = threadIdx.x;
    int base = blockIdx.x * 1024 + t * 4;
    int c0 = 0, c1 = 0, c2 = 0, c3 = 0;
    if (base + 3 < n) {
        int4 v = *(const int4*)(counts + base);
        c0 = v.x; c1 = v.y; c2 = v.z; c3 = v.w;
    } else {
        if (base     < n) c0 = counts[base];
        if (base + 1 < n) c1 = counts[base + 1];
        if (base + 2 < n) c2 = counts[base + 2];
        if (base + 3 < n) c3 = counts[base + 3];
    }
    int tsum = c0 + c1 + c2 + c3;
    int inc = tsum;
    int lane = t & 63, wid = t >> 6;
#pragma unroll
    for (int o = 1; o < 64; o <<= 1) {
        int v = __shfl_up(inc, o);
        if (lane >= o) inc += v;
    }
    __shared__ int wsum[4];
    if (lane == 63) wsum[wid] = inc;
    __syncthreads();
    int woff = 0;
#pragma unroll
    for (int w = 0; w < 4; ++w)
        if (w < wid) woff += wsum[w];
    int excl = woff + inc - tsum;
    int e0 = excl, e1 = excl + c0, e2 = e1 + c1, e3 = e2 + c2;
    if (base + 3 < n) {
        *(int4*)(outp + base) = make_int4(e0, e1, e2, e3);
    } else {
        if (base     < n) outp[base]     = e0;
        if (base + 1 < n) outp[base + 1] = e1;
        if (base + 2 < n) outp[base + 2] = e2;
        if (base + 3 < n) outp[base + 3] = e3;
    }
    if (t == 255) bsums[blockIdx.x] = wsum[0] + wsum[1] + wsum[2] + wsum[3];
}

__global__ void scan_bsums_kernel(int* __restrict__ bsums, int nb)
{
    int lane = threadIdx.x;   // 64 threads
    int carry = 0;
    for (int c = 0; c * 64 < nb; ++c) {
        int i = c * 64 + lane;
        int v = (i < nb) ? bsums[i] : 0;
        int inc = v;
#pragma unroll
        for (int o = 1; o < 64; o <<= 1) {
            int u = __shfl_up(inc, o);
            if (lane >= o) inc += u;
        }
        if (i < nb) bsums[i] = carry + inc - v;
        carry += __shfl(inc, 63);
    }
}

__global__ __launch_bounds__(256) void scan_final_kernel(
    int* __restrict__ outp, const int* __restrict__ bsums, int n, int total)
{
    int i = blockIdx.x * 256 + threadIdx.x;
    if (i < n) outp[i] = outp[i] + bsums[i >> 10];
    if (i == 0) outp[n] = total;   // outp must have n+1 capacity
}

// ---------------------------------------------------------------------------
// Bucket pass C: LDS-atomic local rank; write packed (src<<7)|dstlow to
// sorted_pk at histS[bin*B+b] + rank. Per-bucket runs are contiguous.
// ---------------------------------------------------------------------------
__global__ __launch_bounds__(256) void bucket_scatter_kernel(
    const int* __restrict__ src, const int* __restrict__ dst,
    const int* __restrict__ histS, unsigned int* __restrict__ sorted_pk,
    int E, int B, int R)
{
    __shared__ int h[RMAX];
    __shared__ int basebin[RMAX];
    int b = blockIdx.x, t = threadIdx.x;
    for (int i = t; i < R; i += 256) {
        h[i] = 0;
        basebin[i] = histS[(size_t)i * B + b];
    }
    __syncthreads();
    int base = b * CHUNK;
    for (int i = t; i < CHUNK; i += 256) {
        int e = base + i;
        if (e < E) {
            int d = dst[e];
            int bin = d >> 7;
            int rk = atomicAdd(&h[bin], 1);
            sorted_pk[basebin[bin] + rk] =
                ((unsigned int)src[e] << 7) | (unsigned int)(d & 127);
        }
    }
}

// ---------------------------------------------------------------------------
// Merged build+agg: one block per bucket (128 dst, 512 threads / 8 waves).
// LDS hist/scan/bin of the bucket's contiguous sorted_pk run, then each
// wave runs the 64-lane gather loop on 16 dst, src from LDS.
// ---------------------------------------------------------------------------
__global__ __launch_bounds__(512) void agg_bucket_kernel(
    const int* __restrict__ histS, const unsigned int* __restrict__ sorted_pk,
    const unsigned short* __restrict__ fsb, const float* __restrict__ el,
    const float* __restrict__ er, float* __restrict__ out,
    int N, int E, int B, int R)
{
    __shared__ int buf2[8192];                  // binned src values, 32 KiB
    __shared__ int hist[128], scn[128], cur[128];
    const int r = blockIdx.x;
    const int t = threadIdx.x;
    int start = histS[(size_t)r * B];
    int end = (r + 1 < R) ? histS[(size_t)(r + 1) * B] : E;
    if (start < 0) start = 0;
    if (end < start) end = start;
    if (end > E) end = E;                       // clamps: identity on correct data
    const int cnt = end - start;

    if (t < 128) { hist[t] = 0; cur[t] = 0; }
    __syncthreads();
    // pass 1: histogram over dstlow (coalesced global pk read, LDS int atomics)
    for (int i = t; i < cnt; i += 512)
        atomicAdd(&hist[sorted_pk[start + i] & 127], 1);
    __syncthreads();
    if (t < 128) scn[t] = hist[t];
    __syncthreads();
    for (int o = 1; o < 128; o <<= 1) {
        int v = 0;
        if (t < 128 && t >= o) v = scn[t - o];
        __syncthreads();
        if (t < 128) scn[t] += v;
        __syncthreads();
    }
    // pass 2: bin src values into LDS (scn inclusive; offset = scn - hist)
    const bool use_lds = (cnt <= 8192);
    if (use_lds) {
        for (int i = t; i < cnt; i += 512) {
            unsigned int pk = sorted_pk[start + i];
            int low = (int)(pk & 127u);
            int rk = atomicAdd(&cur[low], 1);
            buf2[(scn[low] - hist[low]) + rk] = (int)(pk >> 7);
        }
    }
    __syncthreads();

    // agg: wave w handles dst r*128 + w*16 + j, j=0..15 (agg_csr loop body)
    const int lane = t & 63;
    const int w = t >> 6;              // 0..7
    const int half = lane >> 5;
    const int c = lane & 31;           // channels 2c, 2c+1
    const int h = c >> 3;
    for (int j = 0; j < 16; ++j) {
        int dl = w * 16 + j;
        int d = r * 128 + dl;
        if (d >= N) break;             // dl increasing -> all later invalid too
        const int k0 = scn[dl] - hist[dl];
        const int k1 = scn[dl];
        const float erh = er[(size_t)d * 4 + h];
        float a0 = 0.f, a1 = 0.f, den = 0.f;
        if (use_lds) {
            int kb = k0;
            for (; kb + 8 <= k1; kb += 8) {
                int s0 = buf2[kb + half];
                int s1 = buf2[kb + 2 + half];
                int s2 = buf2[kb + 4 + half];
                int s3 = buf2[kb + 6 + half];
                float e0 = el[(size_t)s0 * 4 + h];
                float e1 = el[(size_t)s1 * 4 + h];
                float e2 = el[(size_t)s2 * 4 + h];
                float e3 = el[(size_t)s3 * 4 + h];
                unsigned int f0 = *(const unsigned int*)(fsb + (size_t)s0 * O_OUT + 2 * c);
                unsigned int f1 = *(const unsigned int*)(fsb + (size_t)s1 * O_OUT + 2 * c);
                unsigned int f2 = *(const unsigned int*)(fsb + (size_t)s2 * O_OUT + 2 * c);
                unsigned int f3 = *(const unsigned int*)(fsb + (size_t)s3 * O_OUT + 2 * c);
                float w0 = __expf(lrelu(e0 + erh));
                float w1 = __expf(lrelu(e1 + erh));
                float w2 = __expf(lrelu(e2 + erh));
                float w3 = __expf(lrelu(e3 + erh));
                a0 += w0 * bflo(f0); a1 += w0 * bfhi(f0); den += w0;
                a0 += w1 * bflo(f1); a1 += w1 * bfhi(f1); den += w1;
                a0 += w2 * bflo(f2); a1 += w2 * bfhi(f2); den += w2;
                a0 += w3 * bflo(f3); a1 += w3 * bfhi(f3); den += w3;
            }
            for (; kb < k1; kb += 2) {
                int ki = kb + half;
                if (ki < k1) {
                    int s = buf2[ki];
                    float wv = __expf(lrelu(el[(size_t)s * 4 + h] + erh));
                    unsigned int f = *(const unsigned int*)(fsb + (size_t)s * O_OUT + 2 * c);
                    a0 += wv * bflo(f); a1 += wv * bfhi(f); den += wv;
                }
            }
        } else {
            // fallback (cnt > 8192, not expected at bench sizes): filter scan
            for (int i2 = 0; i2 < cnt; i2 += 2) {
                int ki = i2 + half;
                if (ki < cnt) {
                    unsigned int pk = sorted_pk[start + ki];
                    if ((int)(pk & 127u) == dl) {
                        int s = (int)(pk >> 7);
                        float wv = __expf(lrelu(el[(size_t)s * 4 + h] + erh));
                        unsigned int f = *(const unsigned int*)(fsb + (size_t)s * O_OUT + 2 * c);
                        a0 += wv * bflo(f); a1 += wv * bfhi(f); den += wv;
                    }
                }
            }
        }
        a0 += __shfl_xor(a0, 32);
        a1 += __shfl_xor(a1, 32);
        den += __shfl_xor(den, 32);
        if (half == 0) {
            float inv = 1.0f / fmaxf(den, 1e-20f);
            float2* po = (float2*)(out + (size_t)d * O_OUT + 2 * c);
            float2 o = *po;
            o.x += a0 * inv;
            o.y += a1 * inv;
            *po = o;
        }
    }
}

// ---------------------------------------------------------------------------
// Fallback path (small ws): no-max softmax, atomics, bf16 fs.
// ---------------------------------------------------------------------------
__global__ __launch_bounds__(256) void edge_sum_kernel(
    const int* __restrict__ src, const int* __restrict__ dst,
    const float* __restrict__ el, const float* __restrict__ er,
    float* __restrict__ denom, int E)
{
    int e = blockIdx.x * 256 + threadIdx.x;
    if (e >= E) return;
    int s = src[e], d = dst[e];
    float4 l4 = ((const float4*)el)[s];
    float4 r4 = ((const float4*)er)[d];
    unsafeAtomicAdd(&denom[(size_t)d * 4 + 0], __expf(lrelu(l4.x + r4.x)));
    unsafeAtomicAdd(&denom[(size_t)d * 4 + 1], __expf(lrelu(l4.y + r4.y)));
    unsafeAtomicAdd(&denom[(size_t)d * 4 + 2], __expf(lrelu(l4.z + r4.z)));
    unsafeAtomicAdd(&denom[(size_t)d * 4 + 3], __expf(lrelu(l4.w + r4.w)));
}

__global__ __launch_bounds__(256) void agg_atomic_kernel(
    const int* __restrict__ src, const int* __restrict__ dst,
    const unsigned short* __restrict__ fsb, const float* __restrict__ el,
    const float* __restrict__ er, const float* __restrict__ denom,
    float* __restrict__ out, int E)
{
    const int lane = threadIdx.x & 63;
    const int wid = threadIdx.x >> 6;
    int e = blockIdx.x * 4 + wid;
    if (e >= E) return;
    int s = src[e], d = dst[e];
    int h = lane >> 4;
    float v = __expf(lrelu(el[(size_t)s * 4 + h] + er[(size_t)d * 4 + h]));
    float alpha = v / fmaxf(denom[(size_t)d * 4 + h], 1e-20f);
    float fval = __uint_as_float(((unsigned int)fsb[(size_t)s * O_OUT + lane]) << 16);
    unsafeAtomicAdd(&out[(size_t)d * O_OUT + lane], alpha * fval);
}

extern "C" void kernel_launch(void* const* d_in, const int* in_sizes, int n_in,
                              void* d_out, int out_size, void* d_ws, size_t ws_size,
                              hipStream_t stream) {
    const float* feat   = (const float*)d_in[0];
    const float* Wfc    = (const float*)d_in[1];
    const float* attn_l = (const float*)d_in[2];
    const float* attn_r = (const float*)d_in[3];
    const float* Wres   = (const float*)d_in[4];
    const int*   src    = (const int*)d_in[5];
    const int*   dst    = (const int*)d_in[6];

    const int N = in_sizes[0] / F_IN;     // 100000
    const int E = in_sizes[5];            // 3200000
    float* out = (float*)d_out;

    const int R = (N + 127) >> 7;                 // buckets of 128 nodes
    const int B = (E + CHUNK - 1) / CHUNK;        // blocks in bucket passes
    const int nRB = R * B;
    const int nsb = (nRB + 1023) / 1024;

    // layout: el | er | Bf | histT[nRB] | histS[nRB+8] | bsums[1024] |
    //         sorted_pk[E] | fsb
    float* el     = (float*)d_ws;
    float* er     = el + (size_t)N * 4;
    unsigned short* Bf = (unsigned short*)(er + (size_t)N * 4);
    int*   histT  = (int*)(Bf + 32768);
    int*   histS  = histT + nRB;
    int*   bsums  = histS + nRB + 8;
    unsigned int* sorted_pk = (unsigned int*)(bsums + 1024);
    unsigned short* fsb = (unsigned short*)(sorted_pk + E);
    size_t need_main = (size_t)((char*)(fsb + (size_t)N * O_OUT) - (char*)d_ws);

    int nproj = (N + 63) / 64;

    if (ws_size >= need_main && R <= RMAX && nsb <= 1024) {
        wprep_kernel<<<16, 256, 0, stream>>>(Wfc, Wres, Bf);
        proj_mfma_kernel<<<nproj, 256, 0, stream>>>(
            feat, Bf, attn_l, attn_r, fsb, el, er, out, nullptr, N);
        bucket_count_kernel<<<B, 256, 0, stream>>>(dst, histT, E, B, R);
        scan_block_kernel<<<nsb, 256, 0, stream>>>(histT, histS, bsums, nRB);
        scan_bsums_kernel<<<1, 64, 0, stream>>>(bsums, nsb);
        scan_final_kernel<<<(nRB + 255) / 256, 256, 0, stream>>>(histS, bsums, nRB, E);
        bucket_scatter_kernel<<<B, 256, 0, stream>>>(src, dst, histS, sorted_pk, E, B, R);
        agg_bucket_kernel<<<R, 512, 0, stream>>>(
            histS, sorted_pk, fsb, el, er, out, N, E, B, R);
    } else {
        // fallback: denom overlays histT region; fsb right after denom
        float* denom = (float*)histT;                 // [N*4]
        unsigned short* fsb2 = (unsigned short*)(denom + (size_t)N * 4);
        wprep_kernel<<<16, 256, 0, stream>>>(Wfc, Wres, Bf);
        proj_mfma_kernel<<<nproj, 256, 0, stream>>>(
            feat, Bf, attn_l, attn_r, fsb2, el, er, out, denom, N);
        edge_sum_kernel<<<(E + 255) / 256, 256, 0, stream>>>(src, dst, el, er, denom, E);
        agg_atomic_kernel<<<(E + 3) / 4, 256, 0, stream>>>(
            src, dst, fsb2, el, er, denom, out, E);
    }
}